// Round 1
// baseline (177.687 us; speedup 1.0000x reference)
//
#include <hip/hip_runtime.h>
#include <hip/hip_bf16.h>

#define BB 8
#define HH 64
#define WW 64
#define DD 128
#define NH 4
#define HD 32
#define KS 7
#define TS 8
#define HALO 14   // TS + KS - 1
#define SPAD 36   // padded pixel stride in LDS (floats) to break bank aliasing

// ---------------------------------------------------------------------------
// Kernel 1: QKV projection.  x(32768,128) @ w_qkv^T(128,384) + b  -> q,k,v
// laid out as [B][NH][H*W][HD] each.
// Block: 384 threads (6 waves), each thread owns one output column for a
// 32-row tile.  x tile staged in LDS (reads are wave-broadcast).
// ---------------------------------------------------------------------------
__global__ __launch_bounds__(384) void qkv_kernel(
    const float* __restrict__ x, const float* __restrict__ w,
    const float* __restrict__ bqkv,
    float* __restrict__ q, float* __restrict__ k, float* __restrict__ v) {
  __shared__ __align__(16) float xs[32][128];
  const int block_row = blockIdx.x * 32;
  const int tid = threadIdx.x;

  // cooperative load: 32 rows x 32 float4
  for (int idx = tid; idx < 32 * 32; idx += 384) {
    int r = idx >> 5, f = idx & 31;
    float4 t = reinterpret_cast<const float4*>(x)[(size_t)(block_row + r) * 32 + f];
    *reinterpret_cast<float4*>(&xs[r][f * 4]) = t;
  }
  __syncthreads();

  const int c = tid;  // 0..383
  float acc[32];
#pragma unroll
  for (int r = 0; r < 32; r++) acc[r] = 0.f;

  const float* wrow = w + (size_t)c * 128;
  for (int kk = 0; kk < 128; kk += 16) {
    float wv[16];
#pragma unroll
    for (int m = 0; m < 16; m += 4) {
      float4 t = *reinterpret_cast<const float4*>(wrow + kk + m);
      wv[m] = t.x; wv[m + 1] = t.y; wv[m + 2] = t.z; wv[m + 3] = t.w;
    }
#pragma unroll
    for (int r = 0; r < 32; r++) {
#pragma unroll
      for (int m = 0; m < 16; m += 4) {
        float4 xv = *reinterpret_cast<const float4*>(&xs[r][kk + m]);
        acc[r] += xv.x * wv[m] + xv.y * wv[m + 1] + xv.z * wv[m + 2] + xv.w * wv[m + 3];
      }
    }
  }

  const float bias = bqkv[c];
  const int which = c >> 7;          // 0=q 1=k 2=v
  const int cc = c & 127;
  const int head = cc >> 5;
  const int d = cc & 31;
  float* outp = (which == 0) ? q : ((which == 1) ? k : v);

#pragma unroll
  for (int r = 0; r < 32; r++) {
    const int row = block_row + r;   // b*4096 + pix
    const int b = row >> 12;
    const int pix = row & 4095;
    outp[(size_t)(b * NH + head) * 131072 + (size_t)pix * HD + d] = acc[r] + bias;
  }
}

// ---------------------------------------------------------------------------
// Kernel 2: neighborhood attention.  One block per (8x8 pixel tile, head, b).
// Stage 14x14 halo of k and v in LDS (stride SPAD).  4 lanes per pixel
// (8 d-values each); 49 scores in registers, fully unrolled.
// Output written to d_out in (B*H*W, 128) proj-input layout.
// ---------------------------------------------------------------------------
__global__ __launch_bounds__(256) void attn_kernel(
    const float* __restrict__ q, const float* __restrict__ k,
    const float* __restrict__ v, float* __restrict__ out) {
  __shared__ __align__(16) float ks[HALO * HALO * SPAD];
  __shared__ __align__(16) float vs[HALO * HALO * SPAD];

  const int tile = blockIdx.x;       // 0..63
  const int tx = tile >> 3, ty = tile & 7;
  const int head = blockIdx.y, bb = blockIdx.z;
  const size_t bh = ((size_t)bb * NH + head) * 4096;  // pixel base
  const float* kb = k + bh * HD;
  const float* vb = v + bh * HD;
  const float* qb = q + bh * HD;

  const int rstart = min(max(tx * TS - 3, 0), HH - HALO);
  const int cstart = min(max(ty * TS - 3, 0), WW - HALO);
  const int tid = threadIdx.x;

  // cooperative halo load: 196 pixels x 8 float4 (k and v)
  for (int idx = tid; idx < HALO * HALO * 8; idx += 256) {
    const int p = idx >> 3, f = idx & 7;
    const int pr = p / HALO, pc = p % HALO;
    const size_t g = ((size_t)((rstart + pr) * WW + (cstart + pc))) * HD + f * 4;
    *reinterpret_cast<float4*>(&ks[p * SPAD + f * 4]) =
        *reinterpret_cast<const float4*>(kb + g);
    *reinterpret_cast<float4*>(&vs[p * SPAD + f * 4]) =
        *reinterpret_cast<const float4*>(vb + g);
  }
  __syncthreads();

  const int p = tid >> 2;            // pixel within tile, 0..63
  const int lane4 = tid & 3;
  const int px = p >> 3, py = p & 7;
  const int x = tx * TS + px, y = ty * TS + py;
  const int sx = min(max(x - 3, 0), HH - KS);
  const int sy = min(max(y - 3, 0), WW - KS);
  const int wx0 = sx - rstart, wy0 = sy - cstart;
  const int d0 = lane4 * 8;
  const float scale = 0.17677669529663687f;  // 1/sqrt(32)

  float qv[8];
  {
    const float* qp = qb + ((size_t)(x * WW + y)) * HD + d0;
    float4 a = *reinterpret_cast<const float4*>(qp);
    float4 b4 = *reinterpret_cast<const float4*>(qp + 4);
    qv[0] = a.x * scale; qv[1] = a.y * scale; qv[2] = a.z * scale; qv[3] = a.w * scale;
    qv[4] = b4.x * scale; qv[5] = b4.y * scale; qv[6] = b4.z * scale; qv[7] = b4.w * scale;
  }

  float s[49];
#pragma unroll
  for (int n = 0; n < 49; n++) {
    const int i = n / 7, j = n % 7;
    const float* kp = &ks[((wx0 + i) * HALO + (wy0 + j)) * SPAD + d0];
    float4 ka = *reinterpret_cast<const float4*>(kp);
    float4 kb4 = *reinterpret_cast<const float4*>(kp + 4);
    float t = qv[0] * ka.x + qv[1] * ka.y + qv[2] * ka.z + qv[3] * ka.w +
              qv[4] * kb4.x + qv[5] * kb4.y + qv[6] * kb4.z + qv[7] * kb4.w;
    t += __shfl_xor(t, 1);
    t += __shfl_xor(t, 2);
    s[n] = t;
  }

  float m = s[0];
#pragma unroll
  for (int n = 1; n < 49; n++) m = fmaxf(m, s[n]);
  float l = 0.f;
#pragma unroll
  for (int n = 0; n < 49; n++) { s[n] = __expf(s[n] - m); l += s[n]; }
  const float inv = 1.f / l;

  float o[8];
#pragma unroll
  for (int t = 0; t < 8; t++) o[t] = 0.f;
#pragma unroll
  for (int n = 0; n < 49; n++) {
    const int i = n / 7, j = n % 7;
    const float* vp = &vs[((wx0 + i) * HALO + (wy0 + j)) * SPAD + d0];
    float4 va = *reinterpret_cast<const float4*>(vp);
    float4 vb4 = *reinterpret_cast<const float4*>(vp + 4);
    o[0] += s[n] * va.x; o[1] += s[n] * va.y; o[2] += s[n] * va.z; o[3] += s[n] * va.w;
    o[4] += s[n] * vb4.x; o[5] += s[n] * vb4.y; o[6] += s[n] * vb4.z; o[7] += s[n] * vb4.w;
  }

  // write attn output into proj-input layout: row = bb*4096 + pix, col = head*32+d
  float* op = out + ((size_t)bb * 4096 + (size_t)(x * WW + y)) * DD + head * HD + d0;
  *reinterpret_cast<float4*>(op) =
      make_float4(o[0] * inv, o[1] * inv, o[2] * inv, o[3] * inv);
  *reinterpret_cast<float4*>(op + 4) =
      make_float4(o[4] * inv, o[5] * inv, o[6] * inv, o[7] * inv);
}

// ---------------------------------------------------------------------------
// Kernel 3: output projection, in place on d_out.
// Block: 128 threads, 32-row tile staged in LDS before overwrite (safe).
// ---------------------------------------------------------------------------
__global__ __launch_bounds__(128) void proj_kernel(
    const float* __restrict__ wp, const float* __restrict__ bp,
    float* __restrict__ io) {
  __shared__ __align__(16) float xs[32][128];
  const int block_row = blockIdx.x * 32;
  const int tid = threadIdx.x;

  for (int idx = tid; idx < 32 * 32; idx += 128) {
    int r = idx >> 5, f = idx & 31;
    *reinterpret_cast<float4*>(&xs[r][f * 4]) =
        reinterpret_cast<const float4*>(io)[(size_t)(block_row + r) * 32 + f];
  }
  __syncthreads();

  const int c = tid;  // 0..127
  float acc[32];
#pragma unroll
  for (int r = 0; r < 32; r++) acc[r] = 0.f;

  const float* wrow = wp + (size_t)c * 128;
  for (int kk = 0; kk < 128; kk += 16) {
    float wv[16];
#pragma unroll
    for (int m = 0; m < 16; m += 4) {
      float4 t = *reinterpret_cast<const float4*>(wrow + kk + m);
      wv[m] = t.x; wv[m + 1] = t.y; wv[m + 2] = t.z; wv[m + 3] = t.w;
    }
#pragma unroll
    for (int r = 0; r < 32; r++) {
#pragma unroll
      for (int m = 0; m < 16; m += 4) {
        float4 xv = *reinterpret_cast<const float4*>(&xs[r][kk + m]);
        acc[r] += xv.x * wv[m] + xv.y * wv[m + 1] + xv.z * wv[m + 2] + xv.w * wv[m + 3];
      }
    }
  }

  const float bias = bp[c];
#pragma unroll
  for (int r = 0; r < 32; r++) {
    io[(size_t)(block_row + r) * DD + c] = acc[r] + bias;
  }
}

// ---------------------------------------------------------------------------
extern "C" void kernel_launch(void* const* d_in, const int* in_sizes, int n_in,
                              void* d_out, int out_size, void* d_ws, size_t ws_size,
                              hipStream_t stream) {
  const float* x      = (const float*)d_in[0];
  const float* w_qkv  = (const float*)d_in[1];
  const float* b_qkv  = (const float*)d_in[2];
  const float* w_proj = (const float*)d_in[3];
  const float* b_proj = (const float*)d_in[4];
  float* out = (float*)d_out;

  const size_t per = (size_t)BB * NH * HH * WW * HD;  // 4,194,304 floats
  float* q = (float*)d_ws;
  float* k = q + per;
  float* v = k + per;

  // 1) QKV projection: 32768 rows / 32 per block
  qkv_kernel<<<dim3(1024), dim3(384), 0, stream>>>(x, w_qkv, b_qkv, q, k, v);

  // 2) neighborhood attention -> d_out (proj-input layout)
  attn_kernel<<<dim3(64, NH, BB), dim3(256), 0, stream>>>(q, k, v, out);

  // 3) output projection in place
  proj_kernel<<<dim3(1024), dim3(128), 0, stream>>>(w_proj, b_proj, out);
}

// Round 2
// 74.360 us; speedup vs baseline: 2.3895x; 2.3895x over previous
//
#include <hip/hip_runtime.h>
#include <hip/hip_bf16.h>

#define BB 8
#define HH 64
#define WW 64
#define DD 128
#define NH 4
#define HD 32
#define KS 7
#define TS 8
#define HALO 14   // TS + KS - 1
#define SPAD 36   // padded pixel stride in LDS (floats)

typedef __attribute__((ext_vector_type(8))) short short8v;   // 8 bf16 = 4 VGPR
typedef __attribute__((ext_vector_type(4))) float f32x4;

__device__ inline short f2bf(float f) {   // fp32 -> bf16 RNE
  union { float f; unsigned u; } x; x.f = f;
  unsigned r = x.u + 0x7FFFu + ((x.u >> 16) & 1u);
  return (short)(r >> 16);
}

// ---------------------------------------------------------------------------
// bf16-MFMA GEMM #1: qkv = x(32768,128) @ w_qkv^T + b -> q,k,v [B][NH][HW][HD]
// Block 256 thr (4 waves, 2x2), tile 128(M) x 128(N), K=128 in one shot.
// LDS: A,B tiles bf16, byte XOR-swizzle ((row&7)<<4) to kill the 256B-stride
// bank conflict on ds_read_b128 (T2).
// ---------------------------------------------------------------------------
__global__ __launch_bounds__(256) void qkv_mfma(
    const float* __restrict__ x, const float* __restrict__ w,
    const float* __restrict__ bqkv,
    float* __restrict__ q, float* __restrict__ k, float* __restrict__ v) {
  __shared__ __align__(16) short smA[128 * 128];
  __shared__ __align__(16) short smB[128 * 128];
  const int tid = threadIdx.x;
  const int m_tile = blockIdx.x;   // 0..255
  const int n_tile = blockIdx.y;   // 0..2

  const float* Ab = x + (size_t)m_tile * 128 * 128;
  const float* Bb = w + (size_t)n_tile * 128 * 128;
#pragma unroll
  for (int i = 0; i < 8; i++) {
    int idx = tid + i * 256;          // [128 rows][16 8-elem chunks]
    int r = idx >> 4, p = idx & 15;
    const float* ap = Ab + r * 128 + p * 8;
    float4 a0 = *(const float4*)ap;
    float4 a1 = *(const float4*)(ap + 4);
    short8v s;
    s[0] = f2bf(a0.x); s[1] = f2bf(a0.y); s[2] = f2bf(a0.z); s[3] = f2bf(a0.w);
    s[4] = f2bf(a1.x); s[5] = f2bf(a1.y); s[6] = f2bf(a1.z); s[7] = f2bf(a1.w);
    *(short8v*)((char*)smA + ((r * 256 + p * 16) ^ ((r & 7) << 4))) = s;
    const float* bp_ = Bb + r * 128 + p * 8;
    float4 b0 = *(const float4*)bp_;
    float4 b1 = *(const float4*)(bp_ + 4);
    short8v t;
    t[0] = f2bf(b0.x); t[1] = f2bf(b0.y); t[2] = f2bf(b0.z); t[3] = f2bf(b0.w);
    t[4] = f2bf(b1.x); t[5] = f2bf(b1.y); t[6] = f2bf(b1.z); t[7] = f2bf(b1.w);
    *(short8v*)((char*)smB + ((r * 256 + p * 16) ^ ((r & 7) << 4))) = t;
  }
  __syncthreads();

  const int lane = tid & 63;
  const int wid = tid >> 6;
  const int wm = wid >> 1, wn = wid & 1;
  const int l15 = lane & 15, l4 = lane >> 4;

  f32x4 acc[4][4] = {};
  const int rowA0 = wm * 64 + l15;
  const int rowB0 = wn * 64 + l15;
  const int swzA = (rowA0 & 7) << 4;   // row&7 invariant under +16 steps
  const int swzB = (rowB0 & 7) << 4;

#pragma unroll
  for (int ks = 0; ks < 4; ks++) {
    const int cb = ks * 64 + l4 * 16;  // byte col: k-block of 8 bf16 per lane
    short8v a[4], b[4];
#pragma unroll
    for (int i = 0; i < 4; i++) {
      a[i] = *(const short8v*)((const char*)smA + ((((rowA0 + i * 16) * 256) + cb) ^ swzA));
      b[i] = *(const short8v*)((const char*)smB + ((((rowB0 + i * 16) * 256) + cb) ^ swzB));
    }
#pragma unroll
    for (int mi = 0; mi < 4; mi++)
#pragma unroll
      for (int nj = 0; nj < 4; nj++)
        acc[mi][nj] = __builtin_amdgcn_mfma_f32_16x16x32_bf16(a[mi], b[nj], acc[mi][nj], 0, 0, 0);
  }

  // epilogue: C row m -> (b, pix); col n -> (which, head, d)
  const int bblk = m_tile >> 5;        // batch index (4096 rows per b, 128 per tile)
  const int mrow0 = m_tile * 128 + wm * 64;
#pragma unroll
  for (int nj = 0; nj < 4; nj++) {
    const int n = n_tile * 128 + wn * 64 + nj * 16 + l15;
    const int which = n >> 7, head = (n >> 5) & 3, d = n & 31;
    float* outp = (which == 0) ? q : ((which == 1) ? k : v);
    const float bias = bqkv[n];
    float* obase = outp + ((size_t)(bblk * 4 + head)) * 131072 + d;
#pragma unroll
    for (int mi = 0; mi < 4; mi++) {
#pragma unroll
      for (int r = 0; r < 4; r++) {
        const int m = mrow0 + mi * 16 + l4 * 4 + r;
        const int pix = m & 4095;
        obase[(size_t)pix * 32] = acc[mi][nj][r] + bias;
      }
    }
  }
}

// ---------------------------------------------------------------------------
// Kernel 2: neighborhood attention (unchanged from round 0).
// ---------------------------------------------------------------------------
__global__ __launch_bounds__(256) void attn_kernel(
    const float* __restrict__ q, const float* __restrict__ k,
    const float* __restrict__ v, float* __restrict__ out) {
  __shared__ __align__(16) float ks[HALO * HALO * SPAD];
  __shared__ __align__(16) float vs[HALO * HALO * SPAD];

  const int tile = blockIdx.x;       // 0..63
  const int tx = tile >> 3, ty = tile & 7;
  const int head = blockIdx.y, bb = blockIdx.z;
  const size_t bh = ((size_t)bb * NH + head) * 4096;
  const float* kb = k + bh * HD;
  const float* vb = v + bh * HD;
  const float* qb = q + bh * HD;

  const int rstart = min(max(tx * TS - 3, 0), HH - HALO);
  const int cstart = min(max(ty * TS - 3, 0), WW - HALO);
  const int tid = threadIdx.x;

  for (int idx = tid; idx < HALO * HALO * 8; idx += 256) {
    const int p = idx >> 3, f = idx & 7;
    const int pr = p / HALO, pc = p % HALO;
    const size_t g = ((size_t)((rstart + pr) * WW + (cstart + pc))) * HD + f * 4;
    *reinterpret_cast<float4*>(&ks[p * SPAD + f * 4]) =
        *reinterpret_cast<const float4*>(kb + g);
    *reinterpret_cast<float4*>(&vs[p * SPAD + f * 4]) =
        *reinterpret_cast<const float4*>(vb + g);
  }
  __syncthreads();

  const int p = tid >> 2;
  const int lane4 = tid & 3;
  const int px = p >> 3, py = p & 7;
  const int x = tx * TS + px, y = ty * TS + py;
  const int sx = min(max(x - 3, 0), HH - KS);
  const int sy = min(max(y - 3, 0), WW - KS);
  const int wx0 = sx - rstart, wy0 = sy - cstart;
  const int d0 = lane4 * 8;
  const float scale = 0.17677669529663687f;

  float qv[8];
  {
    const float* qp = qb + ((size_t)(x * WW + y)) * HD + d0;
    float4 a = *reinterpret_cast<const float4*>(qp);
    float4 b4 = *reinterpret_cast<const float4*>(qp + 4);
    qv[0] = a.x * scale; qv[1] = a.y * scale; qv[2] = a.z * scale; qv[3] = a.w * scale;
    qv[4] = b4.x * scale; qv[5] = b4.y * scale; qv[6] = b4.z * scale; qv[7] = b4.w * scale;
  }

  float s[49];
#pragma unroll
  for (int n = 0; n < 49; n++) {
    const int i = n / 7, j = n % 7;
    const float* kp = &ks[((wx0 + i) * HALO + (wy0 + j)) * SPAD + d0];
    float4 ka = *reinterpret_cast<const float4*>(kp);
    float4 kb4 = *reinterpret_cast<const float4*>(kp + 4);
    float t = qv[0] * ka.x + qv[1] * ka.y + qv[2] * ka.z + qv[3] * ka.w +
              qv[4] * kb4.x + qv[5] * kb4.y + qv[6] * kb4.z + qv[7] * kb4.w;
    t += __shfl_xor(t, 1);
    t += __shfl_xor(t, 2);
    s[n] = t;
  }

  float m = s[0];
#pragma unroll
  for (int n = 1; n < 49; n++) m = fmaxf(m, s[n]);
  float l = 0.f;
#pragma unroll
  for (int n = 0; n < 49; n++) { s[n] = __expf(s[n] - m); l += s[n]; }
  const float inv = 1.f / l;

  float o[8];
#pragma unroll
  for (int t = 0; t < 8; t++) o[t] = 0.f;
#pragma unroll
  for (int n = 0; n < 49; n++) {
    const int i = n / 7, j = n % 7;
    const float* vp = &vs[((wx0 + i) * HALO + (wy0 + j)) * SPAD + d0];
    float4 va = *reinterpret_cast<const float4*>(vp);
    float4 vb4 = *reinterpret_cast<const float4*>(vp + 4);
    o[0] += s[n] * va.x; o[1] += s[n] * va.y; o[2] += s[n] * va.z; o[3] += s[n] * va.w;
    o[4] += s[n] * vb4.x; o[5] += s[n] * vb4.y; o[6] += s[n] * vb4.z; o[7] += s[n] * vb4.w;
  }

  float* op = out + ((size_t)bb * 4096 + (size_t)(x * WW + y)) * DD + head * HD + d0;
  *reinterpret_cast<float4*>(op) =
      make_float4(o[0] * inv, o[1] * inv, o[2] * inv, o[3] * inv);
  *reinterpret_cast<float4*>(op + 4) =
      make_float4(o[4] * inv, o[5] * inv, o[6] * inv, o[7] * inv);
}

// ---------------------------------------------------------------------------
// bf16-MFMA GEMM #2: out = attn_out(32768,128) @ w_proj^T + b, in place on
// d_out. Each block owns a 128-row band: stages it to LDS (all global reads
// complete before the epilogue writes), so in-place is safe.
// ---------------------------------------------------------------------------
__global__ __launch_bounds__(256) void proj_mfma(
    const float* __restrict__ wp, const float* __restrict__ bp,
    float* __restrict__ io) {
  __shared__ __align__(16) short smA[128 * 128];
  __shared__ __align__(16) short smB[128 * 128];
  const int tid = threadIdx.x;
  const int m_tile = blockIdx.x;   // 0..255

  const float* Ab = io + (size_t)m_tile * 128 * 128;
#pragma unroll
  for (int i = 0; i < 8; i++) {
    int idx = tid + i * 256;
    int r = idx >> 4, p = idx & 15;
    const float* ap = Ab + r * 128 + p * 8;
    float4 a0 = *(const float4*)ap;
    float4 a1 = *(const float4*)(ap + 4);
    short8v s;
    s[0] = f2bf(a0.x); s[1] = f2bf(a0.y); s[2] = f2bf(a0.z); s[3] = f2bf(a0.w);
    s[4] = f2bf(a1.x); s[5] = f2bf(a1.y); s[6] = f2bf(a1.z); s[7] = f2bf(a1.w);
    *(short8v*)((char*)smA + ((r * 256 + p * 16) ^ ((r & 7) << 4))) = s;
    const float* bp_ = wp + r * 128 + p * 8;
    float4 b0 = *(const float4*)bp_;
    float4 b1 = *(const float4*)(bp_ + 4);
    short8v t;
    t[0] = f2bf(b0.x); t[1] = f2bf(b0.y); t[2] = f2bf(b0.z); t[3] = f2bf(b0.w);
    t[4] = f2bf(b1.x); t[5] = f2bf(b1.y); t[6] = f2bf(b1.z); t[7] = f2bf(b1.w);
    *(short8v*)((char*)smB + ((r * 256 + p * 16) ^ ((r & 7) << 4))) = t;
  }
  __syncthreads();

  const int lane = tid & 63;
  const int wid = tid >> 6;
  const int wm = wid >> 1, wn = wid & 1;
  const int l15 = lane & 15, l4 = lane >> 4;

  f32x4 acc[4][4] = {};
  const int rowA0 = wm * 64 + l15;
  const int rowB0 = wn * 64 + l15;
  const int swzA = (rowA0 & 7) << 4;
  const int swzB = (rowB0 & 7) << 4;

#pragma unroll
  for (int ks = 0; ks < 4; ks++) {
    const int cb = ks * 64 + l4 * 16;
    short8v a[4], b[4];
#pragma unroll
    for (int i = 0; i < 4; i++) {
      a[i] = *(const short8v*)((const char*)smA + ((((rowA0 + i * 16) * 256) + cb) ^ swzA));
      b[i] = *(const short8v*)((const char*)smB + ((((rowB0 + i * 16) * 256) + cb) ^ swzB));
    }
#pragma unroll
    for (int mi = 0; mi < 4; mi++)
#pragma unroll
      for (int nj = 0; nj < 4; nj++)
        acc[mi][nj] = __builtin_amdgcn_mfma_f32_16x16x32_bf16(a[mi], b[nj], acc[mi][nj], 0, 0, 0);
  }

  const int mrow0 = m_tile * 128 + wm * 64;
#pragma unroll
  for (int nj = 0; nj < 4; nj++) {
    const int n = wn * 64 + nj * 16 + l15;
    const float bias = bp[n];
#pragma unroll
    for (int mi = 0; mi < 4; mi++) {
#pragma unroll
      for (int r = 0; r < 4; r++) {
        const int m = mrow0 + mi * 16 + l4 * 4 + r;
        io[(size_t)m * DD + n] = acc[mi][nj][r] + bias;
      }
    }
  }
}

// ---------------------------------------------------------------------------
extern "C" void kernel_launch(void* const* d_in, const int* in_sizes, int n_in,
                              void* d_out, int out_size, void* d_ws, size_t ws_size,
                              hipStream_t stream) {
  const float* x      = (const float*)d_in[0];
  const float* w_qkv  = (const float*)d_in[1];
  const float* b_qkv  = (const float*)d_in[2];
  const float* w_proj = (const float*)d_in[3];
  const float* b_proj = (const float*)d_in[4];
  float* out = (float*)d_out;

  const size_t per = (size_t)BB * NH * HH * WW * HD;  // 4,194,304 floats
  float* q = (float*)d_ws;
  float* k = q + per;
  float* v = k + per;

  qkv_mfma<<<dim3(256, 3), dim3(256), 0, stream>>>(x, w_qkv, b_qkv, q, k, v);
  attn_kernel<<<dim3(64, NH, BB), dim3(256), 0, stream>>>(q, k, v, out);
  proj_mfma<<<dim3(256), dim3(256), 0, stream>>>(w_proj, b_proj, out);
}